// Round 1
// baseline (107.337 us; speedup 1.0000x reference)
//
#include <hip/hip_runtime.h>

#define L2_REG 0.01f
#define NTOT 16384
#define NBIN 2048
#define NT   1024

// R10: single-workgroup fusion. All device-wide dependencies (histogram ->
// scan -> scatter -> probe) become __syncthreads() inside one 1024-thread
// block on one CU; entire state lives in LDS (147.7 KB < 160 KB):
//   s_ye  [16384] float2  packed (y, exp(r)) counting-sorted by bin (128 KB)
//   s_off [2048]  int     hist counts -> exclusive prefix -> cursor -> X[b+1]
//   s_suf [2049]  float   bin exp-sums -> suffix sums (s_suf[b] = sum over bins >= b)
// Exact counting sort (no MAXB capacity / overflow), 1 node instead of 4,
// zero workspace usage (harness ws poison becomes irrelevant to us).
__global__ __launch_bounds__(NT) void cox_all(const float* __restrict__ rp,
                                              const float* __restrict__ y,
                                              const int* __restrict__ e,
                                              const float* __restrict__ W,
                                              float* __restrict__ out) {
    __shared__ float2 s_ye[NTOT];
    __shared__ int    s_off[NBIN];
    __shared__ float  s_suf[NBIN + 1];
    __shared__ float  s_wred[16], s_tred[16], s_ered[16];

    const int t = threadIdx.x;
    const int lane = t & 63, wave = t >> 6;

    // ---- P0: zero hist tables + ||W||^2 partials (512 KB, coalesced float4) ----
    s_off[t] = 0; s_off[t + NT] = 0;
    s_suf[t] = 0.f; s_suf[t + NT] = 0.f;
    float ws = 0.f;
    const float4* W4 = reinterpret_cast<const float4*>(W);
#pragma unroll
    for (int i = 0; i < 32; ++i) {
        const float4 w = W4[i * NT + t];
        ws = fmaf(w.x, w.x, ws); ws = fmaf(w.y, w.y, ws);
        ws = fmaf(w.z, w.z, ws); ws = fmaf(w.w, w.w, ws);
    }
#pragma unroll
    for (int o = 32; o; o >>= 1) ws += __shfl_down(ws, o, 64);
    if (lane == 0) s_wred[wave] = ws;
    __syncthreads();

    // ---- P1: histogram (LDS atomics; mean occupancy 8/bin) ----
#pragma unroll
    for (int i = 0; i < NTOT / NT; ++i) {
        const int idx = i * NT + t;
        const float yi = y[idx];
        const float ei = __expf(rp[idx]);
        int bin = (int)(yi * (float)NBIN);
        bin = min(max(bin, 0), NBIN - 1);
        atomicAdd(&s_off[bin], 1);
        atomicAdd(&s_suf[bin], ei);
    }
    __syncthreads();

    // ---- P2: prefix-scan counts -> exclusive offsets X[b] (in-place in s_off),
    //          suffix-scan exp-sums (in-place in s_suf). 2 bins per thread.
    //          All LDS reads are each thread's own slots, done before the first
    //          barrier; all writes after the second -> no read/write race.
    const int   c0  = s_off[2 * t], c1 = s_off[2 * t + 1];
    const float shi = s_suf[NBIN - 1 - 2 * t], slo = s_suf[NBIN - 2 - 2 * t];
    int   cp = c0 + c1;      // thread pair-sum, ascending-bin order
    float sp = shi + slo;    // thread pair-sum, descending-bin order
#pragma unroll
    for (int o = 1; o < 64; o <<= 1) {
        const int   pc = __shfl_up(cp, o, 64);
        const float ps = __shfl_up(sp, o, 64);
        if (lane >= o) { cp += pc; sp += ps; }
    }
    if (lane == 63) { s_tred[wave] = (float)cp; s_ered[wave] = sp; }
    __syncthreads();
    if (t < 16) {   // wave 0 scans the 16 wave partials (counts exact in float)
        float vc = s_tred[t], vs = s_ered[t];
#pragma unroll
        for (int o = 1; o < 16; o <<= 1) {
            const float pc = __shfl_up(vc, o, 64);
            const float ps = __shfl_up(vs, o, 64);
            if (lane >= o) { vc += pc; vs += ps; }
        }
        s_tred[t] = vc; s_ered[t] = vs;
    }
    __syncthreads();
    const int   ci = cp + (wave ? (int)s_tred[wave - 1] : 0);
    const float si = sp + (wave ? s_ered[wave - 1] : 0.f);
    s_off[2 * t]     = ci - c0 - c1;       // X[2t]   (exclusive prefix)
    s_off[2 * t + 1] = ci - c1;            // X[2t+1]
    s_suf[NBIN - 2 - 2 * t] = si;          // suffix incl. at lower bin of pair
    s_suf[NBIN - 1 - 2 * t] = si - slo;    // suffix at higher bin
    if (t == 0) s_suf[NBIN] = 0.f;
    __syncthreads();

    // ---- P3: counting-sort scatter. Cursor IS s_off (atomicAdd); after the
    //          barrier s_off[b] == X[b+1] (inclusive prefix) — reused in P4. ----
#pragma unroll
    for (int i = 0; i < NTOT / NT; ++i) {
        const int idx = i * NT + t;
        const float yi = y[idx];
        const float ei = __expf(rp[idx]);
        int bin = (int)(yi * (float)NBIN);
        bin = min(max(bin, 0), NBIN - 1);
        const int pos = atomicAdd(&s_off[bin], 1);
        s_ye[pos] = make_float2(yi, ei);
    }
    __syncthreads();

    // ---- P4: per-j term = suffix tail (bins > bin_j, exact: bin monotone in y)
    //          + exact within-bin probe over [X[bin], X[bin+1]). ----
    float tsum = 0.f, esum = 0.f;
    for (int i = 0; i < NTOT / NT; ++i) {
        const int idx = i * NT + t;
        const float yj = y[idx];
        int bin = (int)(yj * (float)NBIN);
        bin = min(max(bin, 0), NBIN - 1);
        const int k1 = s_off[bin];                  // X[bin+1]
        const int k0 = bin ? s_off[bin - 1] : 0;    // X[bin]
        float den = (float)(NTOT - k1);             // exact int arithmetic in f32
        float num = s_suf[bin + 1];
        for (int k = k0; k < k1; ++k) {
            const float2 v = s_ye[k];
            const float m = (v.x >= yj) ? 1.f : 0.f;
            den += m;
            num = fmaf(m, v.y, num);
        }
        const float ef = (float)e[idx];
        tsum = fmaf(ef, rp[idx] - __logf(num / den), tsum);
        esum += ef;
    }
#pragma unroll
    for (int o = 32; o; o >>= 1) {
        tsum += __shfl_down(tsum, o, 64);
        esum += __shfl_down(esum, o, 64);
    }
    if (lane == 0) { s_tred[wave] = tsum; s_ered[wave] = esum; }
    __syncthreads();
    if (t == 0) {
        float T_ = 0.f, E_ = 0.f, WS = 0.f;
#pragma unroll
        for (int w = 0; w < 16; ++w) { T_ += s_tred[w]; E_ += s_ered[w]; WS += s_wred[w]; }
        out[0] = -T_ / E_ + L2_REG * sqrtf(WS);
    }
}

extern "C" void kernel_launch(void* const* d_in, const int* in_sizes, int n_in,
                              void* d_out, int out_size, void* d_ws, size_t ws_size,
                              hipStream_t stream) {
    (void)in_sizes; (void)n_in; (void)out_size; (void)d_ws; (void)ws_size;
    cox_all<<<dim3(1), dim3(NT), 0, stream>>>((const float*)d_in[0],
                                              (const float*)d_in[1],
                                              (const int*)d_in[2],
                                              (const float*)d_in[3],
                                              (float*)d_out);
}

// Round 2
// 98.311 us; speedup vs baseline: 1.0918x; 1.0918x over previous
//
#include <hip/hip_runtime.h>

#define L2_REG 0.01f
#define NTOT 16384
#define NBIN 4096
#define NT   1024

// R11: single-WG, probe-free. Counting-sort (y, rp|e-in-LSB) into 4096 bins,
// insertion-sort within bins (globally sorted by y after), then one streaming
// suffix pass: den = NTOT - p, num = running suffix of exp(rp). O(N + inversions)
// LDS work instead of R10's O(sum c^2) divergent probe (~54us -> target ~25us).
// ||W||^2 global stream fused under the LDS-latency-bound sort phase.
// LDS: s_ye 128KB + s_off 16KB + reds ~0.4KB = 144.4KB < 160KB.
__global__ __launch_bounds__(NT) void cox_all(const float* __restrict__ rp,
                                              const float* __restrict__ y,
                                              const int* __restrict__ e,
                                              const float* __restrict__ W,
                                              float* __restrict__ out) {
    __shared__ __align__(16) float2 s_ye[NTOT];   // sorted (y, rp|e) records
    __shared__ __align__(16) int    s_off[NBIN];  // counts -> X[b] -> cursor -> X[b+1]
    __shared__ int   s_isc[16];
    __shared__ float s_sc[16];
    __shared__ float s_r0[16], s_r1[16], s_r2[16];

    const int t = threadIdx.x;
    const int lane = t & 63, wave = t >> 6;

    // ---- A: zero hist; load 16 elements/thread (strided float4, coalesced);
    //         pack e into rp mantissa LSB (<=1 ulp, ~1e-8 on final scalar). ----
#pragma unroll
    for (int k = 0; k < 4; ++k) s_off[k * NT + t] = 0;
    float yv[16]; float rk[16]; int bv[16];
    {
        const float4* y4 = reinterpret_cast<const float4*>(y);
        const float4* r4 = reinterpret_cast<const float4*>(rp);
        const int4*   e4 = reinterpret_cast<const int4*>(e);
#pragma unroll
        for (int k = 0; k < 4; ++k) {
            const float4 yy = y4[k * NT + t];
            const float4 rr = r4[k * NT + t];
            const int4   ee = e4[k * NT + t];
            yv[4*k+0] = yy.x; yv[4*k+1] = yy.y; yv[4*k+2] = yy.z; yv[4*k+3] = yy.w;
            rk[4*k+0] = __int_as_float((__float_as_int(rr.x) & ~1) | (ee.x & 1));
            rk[4*k+1] = __int_as_float((__float_as_int(rr.y) & ~1) | (ee.y & 1));
            rk[4*k+2] = __int_as_float((__float_as_int(rr.z) & ~1) | (ee.z & 1));
            rk[4*k+3] = __int_as_float((__float_as_int(rr.w) & ~1) | (ee.w & 1));
        }
    }
#pragma unroll
    for (int k = 0; k < 16; ++k) {
        int b = (int)(yv[k] * (float)NBIN);
        bv[k] = min(max(b, 0), NBIN - 1);
    }
    __syncthreads();          // s_off zeroed
#pragma unroll
    for (int k = 0; k < 16; ++k) atomicAdd(&s_off[bv[k]], 1);
    __syncthreads();

    // ---- B: exact int prefix scan of 4096 counts -> exclusive offsets X[b].
    //         Thread owns bins [4t, 4t+4). Reads before 1st barrier, writes
    //         after 2nd -> race-free in place. ----
    {
        const int4 c4 = *reinterpret_cast<const int4*>(&s_off[4 * t]);
        const int cs = c4.x + c4.y + c4.z + c4.w;
        int ci = cs;
#pragma unroll
        for (int off = 1; off < 64; off <<= 1) {
            const int p = __shfl_up(ci, off, 64);
            if (lane >= off) ci += p;
        }
        if (lane == 63) s_isc[wave] = ci;
        __syncthreads();
        if (t < 16) {
            int v = s_isc[t];
#pragma unroll
            for (int off = 1; off < 16; off <<= 1) {
                const int p = __shfl_up(v, off, 64);
                if (lane >= off) v += p;
            }
            s_isc[t] = v;
        }
        __syncthreads();
        const int base = ci - cs + (wave ? s_isc[wave - 1] : 0);
        s_off[4*t+0] = base;
        s_off[4*t+1] = base + c4.x;
        s_off[4*t+2] = base + c4.x + c4.y;
        s_off[4*t+3] = base + c4.x + c4.y + c4.z;
    }
    __syncthreads();

    // ---- C: counting-sort scatter via atomic cursor (s_off becomes X[b+1]). ----
#pragma unroll
    for (int k = 0; k < 16; ++k) {
        const int pos = atomicAdd(&s_off[bv[k]], 1);
        s_ye[pos] = make_float2(yv[k], rk[k]);
    }
    __syncthreads();

    // ---- D: within-bin insertion sort (4 bins/thread, mean c=4) with the
    //         512KB ||W||^2 stream fused in: 8 float4 loads issued per bin,
    //         HBM latency hides under the LDS-latency-bound sort walk. ----
    float wsum = 0.f;
    {
        const float4* W4 = reinterpret_cast<const float4*>(W);
        int start = t ? s_off[4 * t - 1] : 0;
        for (int c = 0; c < 4; ++c) {
            const float4 w0 = W4[(c*8+0)*NT + t];
            const float4 w1 = W4[(c*8+1)*NT + t];
            const float4 w2 = W4[(c*8+2)*NT + t];
            const float4 w3 = W4[(c*8+3)*NT + t];
            const float4 w4 = W4[(c*8+4)*NT + t];
            const float4 w5 = W4[(c*8+5)*NT + t];
            const float4 w6 = W4[(c*8+6)*NT + t];
            const float4 w7 = W4[(c*8+7)*NT + t];
            const int k1 = s_off[4 * t + c];
            for (int i = start + 1; i < k1; ++i) {
                const float2 v = s_ye[i];
                int j = i - 1;
                while (j >= start && s_ye[j].x > v.x) { s_ye[j + 1] = s_ye[j]; --j; }
                s_ye[j + 1] = v;
            }
            start = k1;
            wsum = fmaf(w0.x,w0.x,wsum); wsum = fmaf(w0.y,w0.y,wsum);
            wsum = fmaf(w0.z,w0.z,wsum); wsum = fmaf(w0.w,w0.w,wsum);
            wsum = fmaf(w1.x,w1.x,wsum); wsum = fmaf(w1.y,w1.y,wsum);
            wsum = fmaf(w1.z,w1.z,wsum); wsum = fmaf(w1.w,w1.w,wsum);
            wsum = fmaf(w2.x,w2.x,wsum); wsum = fmaf(w2.y,w2.y,wsum);
            wsum = fmaf(w2.z,w2.z,wsum); wsum = fmaf(w2.w,w2.w,wsum);
            wsum = fmaf(w3.x,w3.x,wsum); wsum = fmaf(w3.y,w3.y,wsum);
            wsum = fmaf(w3.z,w3.z,wsum); wsum = fmaf(w3.w,w3.w,wsum);
            wsum = fmaf(w4.x,w4.x,wsum); wsum = fmaf(w4.y,w4.y,wsum);
            wsum = fmaf(w4.z,w4.z,wsum); wsum = fmaf(w4.w,w4.w,wsum);
            wsum = fmaf(w5.x,w5.x,wsum); wsum = fmaf(w5.y,w5.y,wsum);
            wsum = fmaf(w5.z,w5.z,wsum); wsum = fmaf(w5.w,w5.w,wsum);
            wsum = fmaf(w6.x,w6.x,wsum); wsum = fmaf(w6.y,w6.y,wsum);
            wsum = fmaf(w6.z,w6.z,wsum); wsum = fmaf(w6.w,w6.w,wsum);
            wsum = fmaf(w7.x,w7.x,wsum); wsum = fmaf(w7.y,w7.y,wsum);
            wsum = fmaf(w7.z,w7.z,wsum); wsum = fmaf(w7.w,w7.w,wsum);
        }
    }
    __syncthreads();

    // ---- E: streaming suffix pass. Thread owns sorted positions [16t,16t+16).
    //         den = NTOT - p (exact, distinct y), num = suffix sum of exp(rp).
    //         No per-element search; terms consumed in-pass. ----
    float ei[16], rv[16];
    {
        const float4* q4 = reinterpret_cast<const float4*>(s_ye);
#pragma unroll
        for (int m = 0; m < 8; ++m) {
            const float4 q = q4[8 * t + m];
            rv[2*m]   = q.y;
            rv[2*m+1] = q.w;
        }
    }
    float csum = 0.f;
#pragma unroll
    for (int k = 0; k < 16; ++k) { ei[k] = __expf(rv[k]); csum += ei[k]; }
    // block-wide exclusive suffix of per-thread chunk sums
    float s = csum;
#pragma unroll
    for (int off = 1; off < 64; off <<= 1) {
        const float v = __shfl_down(s, off, 64);
        if (lane + off < 64) s += v;
    }
    if (lane == 0) s_sc[wave] = s;     // wave total (inclusive suffix at lane 0)
    __syncthreads();
    if (t < 16) {
        float v = s_sc[t];
#pragma unroll
        for (int off = 1; off < 16; off <<= 1) {
            const float p = __shfl_down(v, off, 64);
            if (t + off < 16) v += p;
        }
        s_sc[t] = v;                   // inclusive suffix over wave partials
    }
    __syncthreads();
    float run = (s - csum) + ((wave < 15) ? s_sc[wave + 1] : 0.f);
    float term = 0.f, ecnt = 0.f;
#pragma unroll
    for (int k = 15; k >= 0; --k) {
        run += ei[k];                  // inclusive suffix at p = 16t + k
        if (__float_as_int(rv[k]) & 1) {
            const int p = 16 * t + k;
            term += rv[k] - __logf(__fdividef(run, (float)(NTOT - p)));
            ecnt += 1.f;
        }
    }
    // ---- reduce term / ecnt / wsum ----
#pragma unroll
    for (int off = 32; off; off >>= 1) {
        term += __shfl_down(term, off, 64);
        ecnt += __shfl_down(ecnt, off, 64);
        wsum += __shfl_down(wsum, off, 64);
    }
    if (lane == 0) { s_r0[wave] = term; s_r1[wave] = ecnt; s_r2[wave] = wsum; }
    __syncthreads();
    if (t == 0) {
        float T = 0.f, E = 0.f, WS = 0.f;
#pragma unroll
        for (int w = 0; w < 16; ++w) { T += s_r0[w]; E += s_r1[w]; WS += s_r2[w]; }
        out[0] = -T / E + L2_REG * sqrtf(WS);
    }
}

extern "C" void kernel_launch(void* const* d_in, const int* in_sizes, int n_in,
                              void* d_out, int out_size, void* d_ws, size_t ws_size,
                              hipStream_t stream) {
    (void)in_sizes; (void)n_in; (void)out_size; (void)d_ws; (void)ws_size;
    cox_all<<<dim3(1), dim3(NT), 0, stream>>>((const float*)d_in[0],
                                              (const float*)d_in[1],
                                              (const int*)d_in[2],
                                              (const float*)d_in[3],
                                              (float*)d_out);
}

// Round 3
// 72.508 us; speedup vs baseline: 1.4804x; 1.3559x over previous
//
#include <hip/hip_runtime.h>

#define L2_REG 0.01f
#define NTOT 16384
#define K    8          // WGs per node (one per XCD)
#define NBL  4096       // local bins per WG
#define GB   (K * NBL)  // 32768 global fine bins; mean occupancy 0.5
#define CAP  3072       // per-WG chunk capacity (mean 2048, ~+11 sigma)
#define NT   1024

// R12: 8-way range-split of the R11 sort pipeline, 2 nodes, R9-proven
// kernel-boundary coherence (no spins, no cooperative launch).
// Node1: WG k scans all inputs, keeps y in [k/8,(k+1)/8), counting-sorts
//        into 4096 local bins (c~0.5 -> trivial insertion sort), publishes
//        sorted chunk + (n_k, S_k=sum exp, wsum_k) to ws; wg0 zeroes acc/ticket.
// Node2: WG k builds cross-WG offset/suffix from pubs, does the per-position
//        suffix walk (den = N - global rank, num = running suffix of exp),
//        atomic ticket emits the final scalar.
// e is packed into rp's mantissa LSB (<=1 ulp; benched absmax 0.0 in R11).

__global__ __launch_bounds__(NT) void cox_sort(const float* __restrict__ rp,
                                               const float* __restrict__ y,
                                               const int* __restrict__ e,
                                               const float* __restrict__ W,
                                               float2* __restrict__ g_ye,
                                               int* __restrict__ pub_n,
                                               float* __restrict__ pub_S,
                                               float* __restrict__ pub_w,
                                               float* __restrict__ acc,
                                               int* __restrict__ cnt2) {
    __shared__ __align__(16) float2 s_ye[CAP];   // 24 KB sorted chunk
    __shared__ __align__(16) int    s_off[NBL];  // 16 KB counts->offsets->cursor
    __shared__ int   s_isc[16];
    __shared__ float s_f1[16], s_f2[16];

    const int t = threadIdx.x, wg = blockIdx.x;
    const int lane = t & 63, wave = t >> 6;

    *reinterpret_cast<int4*>(&s_off[4 * t]) = make_int4(0, 0, 0, 0);

    // ---- load all inputs (16 elem/thread, coalesced float4); pack e into r LSB ----
    float yv[16], rk[16];
    {
        const float4* y4 = reinterpret_cast<const float4*>(y);
        const float4* r4 = reinterpret_cast<const float4*>(rp);
        const int4*   e4 = reinterpret_cast<const int4*>(e);
#pragma unroll
        for (int k = 0; k < 4; ++k) {
            const float4 yy = y4[k * NT + t];
            const float4 rr = r4[k * NT + t];
            const int4   ee = e4[k * NT + t];
            yv[4*k+0] = yy.x; yv[4*k+1] = yy.y; yv[4*k+2] = yy.z; yv[4*k+3] = yy.w;
            rk[4*k+0] = __int_as_float((__float_as_int(rr.x) & ~1) | (ee.x & 1));
            rk[4*k+1] = __int_as_float((__float_as_int(rr.y) & ~1) | (ee.y & 1));
            rk[4*k+2] = __int_as_float((__float_as_int(rr.z) & ~1) | (ee.z & 1));
            rk[4*k+3] = __int_as_float((__float_as_int(rr.w) & ~1) | (ee.w & 1));
        }
    }
    // ---- ||W||^2 partial: own 64 KB slice ----
    float wsum = 0.f;
    {
        const float4* W4 = reinterpret_cast<const float4*>(W) + wg * 4096;
#pragma unroll
        for (int m = 0; m < 4; ++m) {
            const float4 w = W4[m * NT + t];
            wsum = fmaf(w.x, w.x, wsum); wsum = fmaf(w.y, w.y, wsum);
            wsum = fmaf(w.z, w.z, wsum); wsum = fmaf(w.w, w.w, wsum);
        }
    }
    __syncthreads();                       // s_off zeroed

    // ---- histogram own range + exp-sum partial ----
    const int lo = wg * NBL;
    float sp = 0.f;
#pragma unroll
    for (int k = 0; k < 16; ++k) {
        int g = (int)(yv[k] * (float)GB);
        g = min(max(g, 0), GB - 1);
        const unsigned lb = (unsigned)(g - lo);
        if (lb < NBL) { atomicAdd(&s_off[lb], 1); sp += __expf(rk[k]); }
    }
#pragma unroll
    for (int o = 32; o; o >>= 1) {
        sp   += __shfl_down(sp,   o, 64);
        wsum += __shfl_down(wsum, o, 64);
    }
    if (lane == 0) { s_f1[wave] = sp; s_f2[wave] = wsum; }
    __syncthreads();                       // atomics + partials done

    // ---- exact int scan: counts -> exclusive offsets X[b] (4 bins/thread) ----
    const int4 c4 = *reinterpret_cast<const int4*>(&s_off[4 * t]);
    const int cs = c4.x + c4.y + c4.z + c4.w;
    int ci = cs;
#pragma unroll
    for (int o = 1; o < 64; o <<= 1) {
        const int p = __shfl_up(ci, o, 64);
        if (lane >= o) ci += p;
    }
    if (lane == 63) s_isc[wave] = ci;
    __syncthreads();
    if (t < 16) {
        int v = s_isc[t];
#pragma unroll
        for (int o = 1; o < 16; o <<= 1) {
            const int p = __shfl_up(v, o, 64);
            if (lane >= o) v += p;
        }
        s_isc[t] = v;
    }
    __syncthreads();
    {
        const int base = ci - cs + (wave ? s_isc[wave - 1] : 0);
        s_off[4*t+0] = base;
        s_off[4*t+1] = base + c4.x;
        s_off[4*t+2] = base + c4.x + c4.y;
        s_off[4*t+3] = base + c4.x + c4.y + c4.z;
    }
    __syncthreads();                       // offsets ready

    // ---- counting-sort scatter (cursor atomics; s_off becomes X[b+1]) ----
#pragma unroll
    for (int k = 0; k < 16; ++k) {
        int g = (int)(yv[k] * (float)GB);
        g = min(max(g, 0), GB - 1);
        const unsigned lb = (unsigned)(g - lo);
        if (lb < NBL) {
            const int pos = atomicAdd(&s_off[lb], 1);
            if (pos < CAP) s_ye[pos] = make_float2(yv[k], rk[k]);
        }
    }
    __syncthreads();

    // ---- insertion sort own 4 bins (mean c=0.5, max ~8: trivial) ----
    {
        int start = t ? s_off[4 * t - 1] : 0;
#pragma unroll
        for (int c = 0; c < 4; ++c) {
            const int k1 = s_off[4 * t + c];
            for (int i = start + 1; i < k1; ++i) {
                const float2 v = s_ye[i];
                int j = i - 1;
                while (j >= start && s_ye[j].x > v.x) { s_ye[j + 1] = s_ye[j]; --j; }
                s_ye[j + 1] = v;
            }
            start = k1;
        }
    }
    __syncthreads();

    // ---- write sorted chunk + publications ----
    const int n = min(s_isc[15], CAP);
    for (int p = t; p < n; p += NT) g_ye[wg * CAP + p] = s_ye[p];
    if (t == 0) {
        float S = 0.f, WS = 0.f;
#pragma unroll
        for (int w = 0; w < 16; ++w) { S += s_f1[w]; WS += s_f2[w]; }
        pub_n[wg] = n; pub_S[wg] = S; pub_w[wg] = WS;
        if (wg == 0) { acc[0] = 0.f; acc[1] = 0.f; cnt2[0] = 0; }  // for node2 ticket
    }
}

__global__ __launch_bounds__(NT) void cox_terms(const float2* __restrict__ g_ye,
                                                const int* __restrict__ pub_n,
                                                const float* __restrict__ pub_S,
                                                const float* __restrict__ pub_w,
                                                float* __restrict__ acc,
                                                int* __restrict__ cnt2,
                                                float* __restrict__ out) {
    __shared__ int   s_n[K];
    __shared__ float s_S[K];
    __shared__ float s_sc[16], s_r0[16], s_r1[16];

    const int t = threadIdx.x, wg = blockIdx.x;
    const int lane = t & 63, wave = t >> 6;

    if (t < K) { s_n[t] = pub_n[t]; s_S[t] = pub_S[t]; }
    __syncthreads();
    int off = 0; float suf = 0.f;
#pragma unroll
    for (int k = 0; k < K; ++k) {
        if (k < wg) off += s_n[k];     // global rank offset of this chunk
        if (k > wg) suf += s_S[k];     // exp suffix of strictly-higher chunks
    }
    const int n = s_n[wg];
    const float2* chunk = g_ye + wg * CAP;

    // thread owns local positions [3t, 3t+3)
    float rv[3], ei[3];
    float csum = 0.f;
#pragma unroll
    for (int j = 0; j < 3; ++j) {
        const int p = 3 * t + j;
        rv[j] = 0.f; ei[j] = 0.f;
        if (p < n) { const float2 v = chunk[p]; rv[j] = v.y; ei[j] = __expf(v.y); csum += ei[j]; }
    }
    // block-wide exclusive suffix of per-thread chunk sums
    float s = csum;
#pragma unroll
    for (int o = 1; o < 64; o <<= 1) {
        const float v = __shfl_down(s, o, 64);
        if (lane + o < 64) s += v;
    }
    if (lane == 0) s_sc[wave] = s;
    __syncthreads();
    if (t < 16) {
        float v = s_sc[t];
#pragma unroll
        for (int o = 1; o < 16; o <<= 1) {
            const float p = __shfl_down(v, o, 64);
            if (t + o < 16) v += p;
        }
        s_sc[t] = v;
    }
    __syncthreads();
    float run = (s - csum) + ((wave < 15) ? s_sc[wave + 1] : 0.f) + suf;
    float term = 0.f, ecnt = 0.f;
#pragma unroll
    for (int j = 2; j >= 0; --j) {
        const int p = 3 * t + j;
        if (p < n) {
            run += ei[j];              // inclusive suffix at global rank off+p
            if (__float_as_int(rv[j]) & 1) {
                term += rv[j] - __logf(__fdividef(run, (float)(NTOT - (off + p))));
                ecnt += 1.f;
            }
        }
    }
#pragma unroll
    for (int o = 32; o; o >>= 1) {
        term += __shfl_down(term, o, 64);
        ecnt += __shfl_down(ecnt, o, 64);
    }
    if (lane == 0) { s_r0[wave] = term; s_r1[wave] = ecnt; }
    __syncthreads();
    if (t == 0) {
        float T = 0.f, E = 0.f;
#pragma unroll
        for (int w = 0; w < 16; ++w) { T += s_r0[w]; E += s_r1[w]; }
        atomicAdd(&acc[0], T);
        atomicAdd(&acc[1], E);
        __threadfence();
        if (atomicAdd(cnt2, 1) == K - 1) {     // last of 8 blocks
            const float a0 = atomicAdd(&acc[0], 0.f);
            const float a1 = atomicAdd(&acc[1], 0.f);
            float WS = 0.f;
#pragma unroll
            for (int k = 0; k < K; ++k) WS += pub_w[k];
            out[0] = -a0 / a1 + L2_REG * sqrtf(WS);
        }
    }
}

extern "C" void kernel_launch(void* const* d_in, const int* in_sizes, int n_in,
                              void* d_out, int out_size, void* d_ws, size_t ws_size,
                              hipStream_t stream) {
    (void)in_sizes; (void)n_in; (void)out_size; (void)ws_size;
    const float* rp = (const float*)d_in[0];
    const float* y  = (const float*)d_in[1];
    const int*   e  = (const int*)d_in[2];
    const float* W  = (const float*)d_in[3];

    float2* g_ye  = (float2*)d_ws;                 // K*CAP records (192 KB)
    int*    pub_n = (int*)(g_ye + K * CAP);        // [8]
    float*  pub_S = (float*)(pub_n + K);           // [8]
    float*  pub_w = pub_S + K;                     // [8]
    float*  acc   = pub_w + K;                     // [2]
    int*    cnt2  = (int*)(acc + 2);               // [1]

    cox_sort<<<dim3(K), dim3(NT), 0, stream>>>(rp, y, e, W, g_ye,
                                               pub_n, pub_S, pub_w, acc, cnt2);
    cox_terms<<<dim3(K), dim3(NT), 0, stream>>>(g_ye, pub_n, pub_S, pub_w,
                                                acc, cnt2, (float*)d_out);
}

// Round 4
// 72.159 us; speedup vs baseline: 1.4875x; 1.0048x over previous
//
#include <hip/hip_runtime.h>

#define L2_REG 0.01f
#define NTOT 16384
#define K    8          // WGs (one per XCD)
#define NBL  4096       // local bins per WG
#define GB   (K * NBL)  // 32768 global fine bins; mean occupancy 0.5
#define CAP  3072       // per-WG chunk capacity (mean 2048, +24 sigma)
#define NT   1024

// R13: self-sufficient range-split. WG k scans ALL inputs anyway (to filter
// y in [k/8,(k+1)/8)), so it also computes the only cross-WG scalars it needs:
//   off_k = #{elements below range}  (global rank offset)  -- 1 compare/elem
//   suf_k = sum exp(r) above range   (suffix seed)          -- 1 masked fma/elem
// Then: counting-sort own chunk into LDS (4096 bins, c~0.5), insertion sort,
// local suffix walk -> per-chunk (T_k, E_k, WS_k) published with plain stores.
// Node2 = one 64-thread block summing 8 partials. No global record round-trip,
// no atomics, no tickets, no poison-sensitive workspace state.
// e packed into rp mantissa LSB (<=1 ulp; benched absmax 0.0 since R11).

__global__ __launch_bounds__(NT) void cox_sort(const float* __restrict__ rp,
                                               const float* __restrict__ y,
                                               const int* __restrict__ e,
                                               const float* __restrict__ W,
                                               float* __restrict__ pubT,
                                               float* __restrict__ pubE,
                                               float* __restrict__ pubW) {
    __shared__ __align__(16) float2 s_ye[CAP];   // 24 KB sorted chunk
    __shared__ __align__(16) int    s_off[NBL];  // 16 KB counts->offsets->cursor
    __shared__ int   s_isc[16];                  // scan wave partials (bin counts)
    __shared__ int   s_i1[16];                   // bl_cnt wave partials
    __shared__ float s_f1[16], s_f2[16];         // hi_sum / wsum wave partials
    __shared__ float s_sc[16];                   // suffix-scan wave partials
    __shared__ float s_r0[16], s_r1[16];         // term / ecnt wave partials
    __shared__ int   s_OFF;                      // off_k scalar
    __shared__ float s_SUF, s_WS;                // suf_k, ||W||^2 partial scalars

    const int t = threadIdx.x, wg = blockIdx.x;
    const int lane = t & 63, wave = t >> 6;

    *reinterpret_cast<int4*>(&s_off[4 * t]) = make_int4(0, 0, 0, 0);

    // ---- load all inputs (16 elem/thread, coalesced float4); pack e into r LSB ----
    float yv[16], rk[16];
    int   bv[16];
    {
        const float4* y4 = reinterpret_cast<const float4*>(y);
        const float4* r4 = reinterpret_cast<const float4*>(rp);
        const int4*   e4 = reinterpret_cast<const int4*>(e);
#pragma unroll
        for (int k = 0; k < 4; ++k) {
            const float4 yy = y4[k * NT + t];
            const float4 rr = r4[k * NT + t];
            const int4   ee = e4[k * NT + t];
            yv[4*k+0] = yy.x; yv[4*k+1] = yy.y; yv[4*k+2] = yy.z; yv[4*k+3] = yy.w;
            rk[4*k+0] = __int_as_float((__float_as_int(rr.x) & ~1) | (ee.x & 1));
            rk[4*k+1] = __int_as_float((__float_as_int(rr.y) & ~1) | (ee.y & 1));
            rk[4*k+2] = __int_as_float((__float_as_int(rr.z) & ~1) | (ee.z & 1));
            rk[4*k+3] = __int_as_float((__float_as_int(rr.w) & ~1) | (ee.w & 1));
        }
    }
#pragma unroll
    for (int k = 0; k < 16; ++k) {
        int g = (int)(yv[k] * (float)GB);
        bv[k] = min(max(g, 0), GB - 1);
    }
    // ---- ||W||^2 partial: own 64 KB slice ----
    float wsum = 0.f;
    {
        const float4* W4 = reinterpret_cast<const float4*>(W) + wg * 4096;
#pragma unroll
        for (int m = 0; m < 4; ++m) {
            const float4 w = W4[m * NT + t];
            wsum = fmaf(w.x, w.x, wsum); wsum = fmaf(w.y, w.y, wsum);
            wsum = fmaf(w.z, w.z, wsum); wsum = fmaf(w.w, w.w, wsum);
        }
    }
    __syncthreads();                       // s_off zeroed

    // ---- histogram own range + cross-WG scalars (below-count, above-exp-sum) ----
    const int lo = wg * NBL, hi = lo + NBL;
    int   bl = 0;
    float hs = 0.f;
#pragma unroll
    for (int k = 0; k < 16; ++k) {
        const unsigned lb = (unsigned)(bv[k] - lo);
        if (lb < NBL) atomicAdd(&s_off[lb], 1);
        bl += (bv[k] < lo) ? 1 : 0;
        const float ex = __expf(rk[k]);
        hs = fmaf((bv[k] >= hi) ? 1.f : 0.f, ex, hs);
    }
#pragma unroll
    for (int o = 32; o; o >>= 1) {
        bl   += __shfl_down(bl,   o, 64);
        hs   += __shfl_down(hs,   o, 64);
        wsum += __shfl_down(wsum, o, 64);
    }
    if (lane == 0) { s_i1[wave] = bl; s_f1[wave] = hs; s_f2[wave] = wsum; }
    __syncthreads();                       // atomics + partials done

    // ---- exact int scan: counts -> exclusive offsets X[b] (4 bins/thread) ----
    const int4 c4 = *reinterpret_cast<const int4*>(&s_off[4 * t]);
    const int cs = c4.x + c4.y + c4.z + c4.w;
    int ci = cs;
#pragma unroll
    for (int o = 1; o < 64; o <<= 1) {
        const int p = __shfl_up(ci, o, 64);
        if (lane >= o) ci += p;
    }
    if (lane == 63) s_isc[wave] = ci;
    __syncthreads();
    if (t < 16) {
        int v = s_isc[t];
#pragma unroll
        for (int o = 1; o < 16; o <<= 1) {
            const int p = __shfl_up(v, o, 64);
            if (lane >= o) v += p;
        }
        s_isc[t] = v;
    }
    if (t == 64) {                         // wave 1 sums cross-WG scalars in parallel
        int   O = 0; float S = 0.f, Wp = 0.f;
#pragma unroll
        for (int w = 0; w < 16; ++w) { O += s_i1[w]; S += s_f1[w]; Wp += s_f2[w]; }
        s_OFF = O; s_SUF = S; s_WS = Wp;
    }
    __syncthreads();
    {
        const int base = ci - cs + (wave ? s_isc[wave - 1] : 0);
        s_off[4*t+0] = base;
        s_off[4*t+1] = base + c4.x;
        s_off[4*t+2] = base + c4.x + c4.y;
        s_off[4*t+3] = base + c4.x + c4.y + c4.z;
    }
    __syncthreads();                       // offsets ready

    // ---- counting-sort scatter (cursor atomics; s_off becomes X[b+1]) ----
#pragma unroll
    for (int k = 0; k < 16; ++k) {
        const unsigned lb = (unsigned)(bv[k] - lo);
        if (lb < NBL) {
            const int pos = atomicAdd(&s_off[lb], 1);
            if (pos < CAP) s_ye[pos] = make_float2(yv[k], rk[k]);
        }
    }
    __syncthreads();

    // ---- insertion sort own 4 bins (mean c=0.5: trivial) ----
    {
        int start = t ? s_off[4 * t - 1] : 0;
#pragma unroll
        for (int c = 0; c < 4; ++c) {
            const int k1 = s_off[4 * t + c];
            for (int i = start + 1; i < k1; ++i) {
                const float2 v = s_ye[i];
                int j = i - 1;
                while (j >= start && s_ye[j].x > v.x) { s_ye[j + 1] = s_ye[j]; --j; }
                s_ye[j + 1] = v;
            }
            start = k1;
        }
    }
    __syncthreads();

    // ---- local suffix walk: thread owns local positions [3t, 3t+3).
    //      den = NTOT - (off_k + p), num = local suffix + suf_k. ----
    const int n = min(s_isc[15], CAP);
    const int OFF = s_OFF;
    float rv[3], ei[3];
    float csum = 0.f;
#pragma unroll
    for (int j = 0; j < 3; ++j) {
        const int p = 3 * t + j;
        rv[j] = 0.f; ei[j] = 0.f;
        if (p < n) { const float2 v = s_ye[p]; rv[j] = v.y; ei[j] = __expf(v.y); csum += ei[j]; }
    }
    float s = csum;
#pragma unroll
    for (int o = 1; o < 64; o <<= 1) {
        const float v = __shfl_down(s, o, 64);
        if (lane + o < 64) s += v;
    }
    if (lane == 0) s_sc[wave] = s;
    __syncthreads();
    if (t < 16) {
        float v = s_sc[t];
#pragma unroll
        for (int o = 1; o < 16; o <<= 1) {
            const float p = __shfl_down(v, o, 64);
            if (t + o < 16) v += p;
        }
        s_sc[t] = v;
    }
    __syncthreads();
    float run = (s - csum) + ((wave < 15) ? s_sc[wave + 1] : 0.f) + s_SUF;
    float term = 0.f, ecnt = 0.f;
#pragma unroll
    for (int j = 2; j >= 0; --j) {
        const int p = 3 * t + j;
        if (p < n) {
            run += ei[j];                  // inclusive suffix at global rank OFF+p
            if (__float_as_int(rv[j]) & 1) {
                term += rv[j] - __logf(__fdividef(run, (float)(NTOT - (OFF + p))));
                ecnt += 1.f;
            }
        }
    }
#pragma unroll
    for (int o = 32; o; o >>= 1) {
        term += __shfl_down(term, o, 64);
        ecnt += __shfl_down(ecnt, o, 64);
    }
    if (lane == 0) { s_r0[wave] = term; s_r1[wave] = ecnt; }
    __syncthreads();
    if (t == 0) {
        float T = 0.f, E = 0.f;
#pragma unroll
        for (int w = 0; w < 16; ++w) { T += s_r0[w]; E += s_r1[w]; }
        pubT[wg] = T; pubE[wg] = E; pubW[wg] = s_WS;   // plain stores; kernel
    }                                                   // boundary is the fence
}

// Node2: one tiny block folds the 8 published partials into the scalar.
__global__ __launch_bounds__(64) void cox_fin(const float* __restrict__ pubT,
                                              const float* __restrict__ pubE,
                                              const float* __restrict__ pubW,
                                              float* __restrict__ out) {
    const int t = threadIdx.x;
    float T = 0.f, E = 0.f, WS = 0.f;
    if (t < K) { T = pubT[t]; E = pubE[t]; WS = pubW[t]; }
#pragma unroll
    for (int o = 4; o; o >>= 1) {
        T  += __shfl_down(T,  o, 64);
        E  += __shfl_down(E,  o, 64);
        WS += __shfl_down(WS, o, 64);
    }
    if (t == 0) out[0] = -T / E + L2_REG * sqrtf(WS);
}

extern "C" void kernel_launch(void* const* d_in, const int* in_sizes, int n_in,
                              void* d_out, int out_size, void* d_ws, size_t ws_size,
                              hipStream_t stream) {
    (void)in_sizes; (void)n_in; (void)out_size; (void)ws_size;
    float* pubT = (float*)d_ws;            // [8]
    float* pubE = pubT + K;                // [8]
    float* pubW = pubE + K;                // [8]

    cox_sort<<<dim3(K), dim3(NT), 0, stream>>>((const float*)d_in[0],
                                               (const float*)d_in[1],
                                               (const int*)d_in[2],
                                               (const float*)d_in[3],
                                               pubT, pubE, pubW);
    cox_fin<<<dim3(1), dim3(64), 0, stream>>>(pubT, pubE, pubW, (float*)d_out);
}